// Round 6
// baseline (612.631 us; speedup 1.0000x reference)
//
#include <hip/hip_runtime.h>

#define EPSV 1e-7f

typedef __bf16 bf16x8 __attribute__((ext_vector_type(8)));
typedef float  f32x4  __attribute__((ext_vector_type(4)));
typedef unsigned int   u32x4 __attribute__((ext_vector_type(4)));
typedef unsigned short u16x8 __attribute__((ext_vector_type(8)));

__device__ __forceinline__ unsigned short f2bf(float f) {
    unsigned int u = __float_as_uint(f);
    return (unsigned short)((u + 0x7FFFu + ((u >> 16) & 1u)) >> 16);
}
__device__ __forceinline__ float bf2f(unsigned short u) {
    return __uint_as_float(((unsigned int)u) << 16);
}
__device__ __forceinline__ void split2(float f, unsigned short& hi, unsigned short& lo) {
    hi = f2bf(f);
    lo = f2bf(f - bf2f(hi));
}
__device__ __forceinline__ unsigned int packhl(float f) {
    unsigned short hi, lo; split2(f, hi, lo);
    return ((unsigned int)hi << 16) | (unsigned int)lo;
}
__device__ __forceinline__ float sigf(float x) {
    return 1.0f / (1.0f + __expf(-x));
}
__device__ __forceinline__ float tanhfast(float x) {
    float cx = fminf(fmaxf(x, -15.0f), 15.0f);
    float e = __expf(2.0f * cx);
    return (e - 1.0f) / (e + 1.0f);
}

#define MFMA16(A, B, C) __builtin_amdgcn_mfma_f32_16x16x32_bf16(A, B, C, 0, 0, 0)
#define BC8(x) __builtin_bit_cast(bf16x8, x)
// same-wave LDS write->read ordering (no s_barrier needed: single-wave block)
#define LGKM0() do {                                     \
    asm volatile("s_waitcnt lgkmcnt(0)" ::: "memory");   \
    __builtin_amdgcn_sched_barrier(0);                   \
} while (0)

#define HS 36   // hbuf row stride (u32); [16][32] used; 144B rows (16B-aligned, 2-way banks)
#define TS 68   // tbuf row stride (u32); [16][64] used; 272B rows

// ONE wave (64 threads) per block owns 16 batch rows for the whole sequence.
// No inter-wave communication, NO barriers. All GEMMs bf16 hi/lo (fp32-grade).
// Col-tile->gate interleave makes LSTM gates fully per-lane (zero shuffles).
// LDS (wave-private) only for h / latest / hidden transposes, packed (hi<<16)|lo.
__global__ __launch_bounds__(64, 1) void tutina_kernel(
    const float* __restrict__ history, const float* __restrict__ control,
    const float* __restrict__ forecasts,
    const float* __restrict__ h_mean, const float* __restrict__ h_var,
    const float* __restrict__ c_mean, const float* __restrict__ c_var,
    const float* __restrict__ f_mean, const float* __restrict__ f_var,
    const float* __restrict__ conv_w, const float* __restrict__ conv_b,
    const float* __restrict__ lstm_k, const float* __restrict__ lstm_rk,
    const float* __restrict__ lstm_b,
    const float* __restrict__ w1, const float* __restrict__ b1,
    const float* __restrict__ w2, const float* __restrict__ b2,
    float* __restrict__ out)
{
    __shared__ unsigned int hbuf[16 * HS];   // h transpose, packed hi|lo
    __shared__ unsigned int tbuf[16 * TS];   // latest / hidden transpose, packed
    __shared__ float fcs[48 * 64];           // fc conv: [t][row*4+unit] fp32

    const int lane = threadIdx.x & 63;
    const int l15  = lane & 15;
    const int l4   = lane >> 4;
    const int b0   = blockIdx.x * 16;

    // ---------------- LSTM weight fragments (B), hi/lo, x-norm folded ----------------
    // col-tile ct covers z-cols 16ct..16ct+15; lane's col j = (ct>>1)*32 + (ct&1)*16 + l15
    // => per lane, tiles {0,2,4,6} are gates i,f,g,o of unit l15; {1,3,5,7} of unit 16+l15.
    bf16x8 fK0h[8], fK0l[8], fK1h[8], fK1l[8], fRh[8], fRl[8];
    float bz[8];
#pragma unroll
    for (int ct = 0; ct < 8; ++ct) {
        const int j = (ct >> 1) * 32 + (ct & 1) * 16 + l15;
        float dz = 0.f;
        u16x8 h, l;
        unsigned short hh, ll;
#pragma unroll
        for (int i = 0; i < 8; i++) {            // k = 0..31 (x, folded)
            int k = l4 * 8 + i;
            float sv = 1.0f / fmaxf(sqrtf(h_var[k]), EPSV);
            float w  = lstm_k[k * 128 + j] * sv;
            dz += h_mean[k] * w;
            split2(w, hh, ll); h[i] = hh; l[i] = ll;
        }
        fK0h[ct] = BC8(h); fK0l[ct] = BC8(l);
#pragma unroll
        for (int i = 0; i < 8; i++) {            // k = 32..63 (x, folded)
            int k = 32 + l4 * 8 + i;
            float sv = 1.0f / fmaxf(sqrtf(h_var[k]), EPSV);
            float w  = lstm_k[k * 128 + j] * sv;
            dz += h_mean[k] * w;
            split2(w, hh, ll); h[i] = hh; l[i] = ll;
        }
        fK1h[ct] = BC8(h); fK1l[ct] = BC8(l);
#pragma unroll
        for (int i = 0; i < 8; i++) {            // recurrent k = 0..31 (plain)
            int k = l4 * 8 + i;
            float w = lstm_rk[k * 128 + j];
            split2(w, hh, ll); h[i] = hh; l[i] = ll;
        }
        fRh[ct] = BC8(h); fRl[ct] = BC8(l);
        dz += __shfl_xor(dz, 16, 64);
        dz += __shfl_xor(dz, 32, 64);
        bz[ct] = lstm_b[j] - dz;
    }

    // ---------------- fc conv precompute (fp32, wave-private) ----------------
    {
        float fm  = f_mean[0];
        float fsc = 1.0f / fmaxf(sqrtf(f_var[0]), EPSV);
        for (int cell = lane; cell < 48 * 64; cell += 64) {
            int u = cell & 3, r = (cell >> 2) & 15, t = cell >> 6;
            const float* fp = forecasts + ((size_t)(b0 + r) * 49 + t) * 8;
            float acc = conv_b[u];
#pragma unroll
            for (int k = 0; k < 8; k++) {
                acc += (fp[k]     - fm) * fsc * conv_w[k * 4 + u];
                acc += (fp[8 + k] - fm) * fsc * conv_w[32 + k * 4 + u];
            }
            fcs[cell] = acc;
        }
    }

    // ---------------- h = 0 init; cell state ----------------
#pragma unroll
    for (int g = 0; g < 2; ++g)
#pragma unroll
        for (int q = 0; q < 4; ++q)
            hbuf[(l4 * 4 + q) * HS + g * 16 + l15] = 0;
    float cA[4] = {0.f, 0.f, 0.f, 0.f};
    float cB[4] = {0.f, 0.f, 0.f, 0.f};

    // packed-LDS reader: rows l15, cols col0 + 8*l4 .. +7 -> hi/lo frags
    auto read_pack = [&](const unsigned int* buf, int stride, int col0,
                         bf16x8& H, bf16x8& L) {
        const unsigned int* p = &buf[l15 * stride + col0 + l4 * 8];
        u32x4 r0 = *(const u32x4*)p;
        u32x4 r1 = *(const u32x4*)(p + 4);
        u32x4 hw, lw;
        hw[0] = (r0[1] & 0xFFFF0000u) | (r0[0] >> 16);
        hw[1] = (r0[3] & 0xFFFF0000u) | (r0[2] >> 16);
        hw[2] = (r1[1] & 0xFFFF0000u) | (r1[0] >> 16);
        hw[3] = (r1[3] & 0xFFFF0000u) | (r1[2] >> 16);
        lw[0] = (r0[1] << 16) | (r0[0] & 0xFFFFu);
        lw[1] = (r0[3] << 16) | (r0[2] & 0xFFFFu);
        lw[2] = (r1[1] << 16) | (r1[0] & 0xFFFFu);
        lw[3] = (r1[3] << 16) | (r1[2] & 0xFFFFu);
        H = BC8(hw); L = BC8(lw);
    };

    // z-GEMM (72 MFMA) + per-lane gates; writes h_new into hbuf
    auto lstm_step = [&](bf16x8 a0h, bf16x8 a0l, bf16x8 a1h, bf16x8 a1l,
                         bf16x8 a2h, bf16x8 a2l) {
        f32x4 z[8];
#pragma unroll
        for (int ct = 0; ct < 8; ++ct) {
            f32x4 acc = {0.f, 0.f, 0.f, 0.f};
            acc = MFMA16(a0h, fK0h[ct], acc);
            acc = MFMA16(a1h, fK1h[ct], acc);
            acc = MFMA16(a2h, fRh[ct],  acc);
            acc = MFMA16(a0l, fK0h[ct], acc);
            acc = MFMA16(a1l, fK1h[ct], acc);
            acc = MFMA16(a2l, fRh[ct],  acc);
            acc = MFMA16(a0h, fK0l[ct], acc);
            acc = MFMA16(a1h, fK1l[ct], acc);
            acc = MFMA16(a2h, fRl[ct],  acc);
            z[ct] = acc;
        }
        auto gate4 = [&](const f32x4& zi4, const f32x4& zf4, const f32x4& zg4,
                         const f32x4& zo4, float bi, float bfv, float bgv,
                         float bov, float c[4], int colu) {
#pragma unroll
            for (int q = 0; q < 4; ++q) {
                float zi = zi4[q] + bi, zf = zf4[q] + bfv;
                float zg = zg4[q] + bgv, zo = zo4[q] + bov;
                c[q] = sigf(zf) * c[q] + sigf(zi) * tanhfast(zg);
                float hv = sigf(zo) * tanhfast(c[q]);
                hbuf[(l4 * 4 + q) * HS + colu] = packhl(hv);
            }
        };
        gate4(z[0], z[2], z[4], z[6], bz[0], bz[2], bz[4], bz[6], cA, l15);
        gate4(z[1], z[3], z[5], z[7], bz[1], bz[3], bz[5], bz[7], cB, 16 + l15);
    };

    // ---------------- encoder: 168 steps, zero barriers ----------------
    const float* hp = history + (size_t)(b0 + l15) * (168 * 64);
    const int o1 = l4 * 8, o2 = 32 + l4 * 8;
    f32x4 va0 = *(const f32x4*)(hp + o1),      va1 = *(const f32x4*)(hp + o1 + 4);
    f32x4 va2 = *(const f32x4*)(hp + o2),      va3 = *(const f32x4*)(hp + o2 + 4);
    f32x4 vb0 = *(const f32x4*)(hp + 64 + o1), vb1 = *(const f32x4*)(hp + 64 + o1 + 4);
    f32x4 vb2 = *(const f32x4*)(hp + 64 + o2), vb3 = *(const f32x4*)(hp + 64 + o2 + 4);

    for (int t = 0; t < 168; ++t) {
        u16x8 xh_, xl_;
        unsigned short hh, ll;
#pragma unroll
        for (int i = 0; i < 4; i++) { split2(va0[i], hh, ll); xh_[i] = hh; xl_[i] = ll; }
#pragma unroll
        for (int i = 0; i < 4; i++) { split2(va1[i], hh, ll); xh_[4+i] = hh; xl_[4+i] = ll; }
        bf16x8 a0h = BC8(xh_), a0l = BC8(xl_);
#pragma unroll
        for (int i = 0; i < 4; i++) { split2(va2[i], hh, ll); xh_[i] = hh; xl_[i] = ll; }
#pragma unroll
        for (int i = 0; i < 4; i++) { split2(va3[i], hh, ll); xh_[4+i] = hh; xl_[4+i] = ll; }
        bf16x8 a1h = BC8(xh_), a1l = BC8(xl_);

        va0 = vb0; va1 = vb1; va2 = vb2; va3 = vb3;
        const float* np = hp + (size_t)((t < 166) ? t + 2 : 167) * 64;
        vb0 = *(const f32x4*)(np + o1); vb1 = *(const f32x4*)(np + o1 + 4);
        vb2 = *(const f32x4*)(np + o2); vb3 = *(const f32x4*)(np + o2 + 4);

        LGKM0();   // h writes from previous step done
        bf16x8 a2h, a2l;
        read_pack(hbuf, HS, 0, a2h, a2l);
        lstm_step(a0h, a0l, a1h, a1l, a2h, a2l);
    }

    // ---------------- MLP weight fragments (loaded post-encoder) ----------------
    bf16x8 w1h0[4], w1l0[4], w1h1[4], w1l1[4], w2h0[4], w2l0[4], w2h1[4], w2l1[4];
    float b1j[4], b2j[4];
#pragma unroll
    for (int m = 0; m < 4; ++m) {
        const int j = m * 16 + l15;
        float d1 = 0.f;
        u16x8 h, l;
        unsigned short hh, ll;
#pragma unroll
        for (int i = 0; i < 8; i++) {            // cat k 0..31 = h (plain)
            int k = l4 * 8 + i;
            float w = w1[k * 64 + j];
            split2(w, hh, ll); h[i] = hh; l[i] = ll;
        }
        w1h0[m] = BC8(h); w1l0[m] = BC8(l);
#pragma unroll
        for (int i = 0; i < 8; i++) {            // cat k 32..63: cn(fold)/fc/pad
            int k = 32 + l4 * 8 + i;
            float w = 0.f;
            if (k < 52) {
                w = w1[k * 64 + j];
                if (k < 48) {
                    float sv = 1.0f / fmaxf(sqrtf(c_var[k - 32]), EPSV);
                    w *= sv;
                    d1 += c_mean[k - 32] * w;
                }
            }
            split2(w, hh, ll); h[i] = hh; l[i] = ll;
        }
        w1h1[m] = BC8(h); w1l1[m] = BC8(l);
#pragma unroll
        for (int i = 0; i < 8; i++) {            // w2 k 0..31
            int k = l4 * 8 + i;
            float w = w2[k * 64 + j];
            split2(w, hh, ll); h[i] = hh; l[i] = ll;
        }
        w2h0[m] = BC8(h); w2l0[m] = BC8(l);
#pragma unroll
        for (int i = 0; i < 8; i++) {            // w2 k 32..63
            int k = 32 + l4 * 8 + i;
            float w = w2[k * 64 + j];
            split2(w, hh, ll); h[i] = hh; l[i] = ll;
        }
        w2h1[m] = BC8(h); w2l1[m] = BC8(l);
        d1 += __shfl_xor(d1, 16, 64);
        d1 += __shfl_xor(d1, 32, 64);
        b1j[m] = b1[j] - d1;
        b2j[m] = b2[j];
    }

    // ---------------- latest = history[:, -1, :] (C/D layout) ----------------
    float lat[4][4];
#pragma unroll
    for (int m = 0; m < 4; ++m)
#pragma unroll
        for (int q = 0; q < 4; ++q)
            lat[m][q] = history[((size_t)(b0 + l4 * 4 + q) * 168 + 167) * 64 + m * 16 + l15];

    // control prefetch (lane (l15, l4<2) loads cn[row l15][8*l4 .. +7], raw)
    const float* cp = control + (size_t)(b0 + l15) * (48 * 16);
    f32x4 cr0 = {0.f,0.f,0.f,0.f}, cr1 = {0.f,0.f,0.f,0.f};
    if (l4 < 2) {
        cr0 = *(const f32x4*)(cp + l4 * 8);
        cr1 = *(const f32x4*)(cp + l4 * 8 + 4);
    }

    // ---------------- MLP phase (uses h in hbuf; updates lat) ----------------
    auto mlp_phase = [&](int t, int tpre) {
        LGKM0();   // h writes done
        bf16x8 m0h, m0l;
        read_pack(hbuf, HS, 0, m0h, m0l);
        u16x8 mh = {0,0,0,0,0,0,0,0}, ml = {0,0,0,0,0,0,0,0};
        unsigned short hh, ll;
        if (l4 < 2) {
#pragma unroll
            for (int i = 0; i < 4; i++) { split2(cr0[i], hh, ll); mh[i] = hh; ml[i] = ll; }
#pragma unroll
            for (int i = 0; i < 4; i++) { split2(cr1[i], hh, ll); mh[4+i] = hh; ml[4+i] = ll; }
        } else if (l4 == 2) {
            f32x4 f = *(const f32x4*)&fcs[t * 64 + l15 * 4];
#pragma unroll
            for (int i = 0; i < 4; i++) { split2(f[i], hh, ll); mh[i] = hh; ml[i] = ll; }
        }
        bf16x8 m1h = BC8(mh), m1l = BC8(ml);
        // prefetch next control slice (floats across the MFMA phase)
        if (l4 < 2) {
            cr0 = *(const f32x4*)(cp + tpre * 16 + l4 * 8);
            cr1 = *(const f32x4*)(cp + tpre * 16 + l4 * 8 + 4);
        }
        f32x4 hacc[4];
#pragma unroll
        for (int m = 0; m < 4; ++m) {
            f32x4 acc = {0.f, 0.f, 0.f, 0.f};
            acc = MFMA16(m0h, w1h0[m], acc);
            acc = MFMA16(m1h, w1h1[m], acc);
            acc = MFMA16(m0l, w1h0[m], acc);
            acc = MFMA16(m1l, w1h1[m], acc);
            acc = MFMA16(m0h, w1l0[m], acc);
            acc = MFMA16(m1h, w1l1[m], acc);
            hacc[m] = acc;
        }
#pragma unroll
        for (int m = 0; m < 4; ++m)
#pragma unroll
            for (int q = 0; q < 4; ++q) {
                float hv = fmaxf(hacc[m][q] + b1j[m], 0.f);
                tbuf[(l4 * 4 + q) * TS + m * 16 + l15] = packhl(hv);
            }
        LGKM0();   // hidden transpose done
        bf16x8 h0h, h0l, h1h, h1l;
        read_pack(tbuf, TS, 0,  h0h, h0l);
        read_pack(tbuf, TS, 32, h1h, h1l);
#pragma unroll
        for (int m = 0; m < 4; ++m) {
            f32x4 acc = {0.f, 0.f, 0.f, 0.f};
            acc = MFMA16(h0h, w2h0[m], acc);
            acc = MFMA16(h1h, w2h1[m], acc);
            acc = MFMA16(h0l, w2h0[m], acc);
            acc = MFMA16(h1l, w2h1[m], acc);
            acc = MFMA16(h0h, w2l0[m], acc);
            acc = MFMA16(h1h, w2l1[m], acc);
#pragma unroll
            for (int q = 0; q < 4; ++q)
                lat[m][q] += acc[q] + b2j[m];
        }
    };

    // post-encoder MLP: uses cn[0]; keep creg at t=0 for decoder iter 0
    mlp_phase(0, 0);

    // ---------------- decoder: 48 steps ----------------
    for (int t = 0; t < 48; ++t) {
        // stage xn = latest (raw; x-norm folded into K) into tbuf
#pragma unroll
        for (int m = 0; m < 4; ++m)
#pragma unroll
            for (int q = 0; q < 4; ++q)
                tbuf[(l4 * 4 + q) * TS + m * 16 + l15] = packhl(lat[m][q]);
        LGKM0();
        bf16x8 a0h, a0l, a1h, a1l, a2h, a2l;
        read_pack(tbuf, TS, 0,  a0h, a0l);
        read_pack(tbuf, TS, 32, a1h, a1l);
        read_pack(hbuf, HS, 0,  a2h, a2l);
        lstm_step(a0h, a0l, a1h, a1l, a2h, a2l);     // writes h_new to hbuf
        mlp_phase(t, (t < 47) ? t + 1 : 47);          // reads h_new (lgkm-waited)
        // store preds[t] = latest2
#pragma unroll
        for (int m = 0; m < 4; ++m)
#pragma unroll
            for (int q = 0; q < 4; ++q)
                out[((size_t)(b0 + l4 * 4 + q) * 48 + t) * 64 + m * 16 + l15] = lat[m][q];
    }
}

extern "C" void kernel_launch(void* const* d_in, const int* in_sizes, int n_in,
                              void* d_out, int out_size, void* d_ws, size_t ws_size,
                              hipStream_t stream) {
    tutina_kernel<<<dim3(256), dim3(64), 0, stream>>>(
        (const float*)d_in[0],  (const float*)d_in[1],  (const float*)d_in[2],
        (const float*)d_in[3],  (const float*)d_in[4],  (const float*)d_in[5],
        (const float*)d_in[6],  (const float*)d_in[7],  (const float*)d_in[8],
        (const float*)d_in[9],  (const float*)d_in[10], (const float*)d_in[11],
        (const float*)d_in[12], (const float*)d_in[13], (const float*)d_in[14],
        (const float*)d_in[15], (const float*)d_in[16], (const float*)d_in[17],
        (float*)d_out);
}

// Round 7
// 186.122 us; speedup vs baseline: 3.2916x; 3.2916x over previous
//
#include <hip/hip_runtime.h>

#define EPSV 1e-7f

typedef __bf16 bf16x8 __attribute__((ext_vector_type(8)));
typedef float  f32x4  __attribute__((ext_vector_type(4)));
typedef unsigned int   u32x4 __attribute__((ext_vector_type(4)));
typedef unsigned short u16x8 __attribute__((ext_vector_type(8)));
typedef unsigned short u16x4 __attribute__((ext_vector_type(4)));

// ---- rne bf16 helpers (setup/one-time paths only) ----
__device__ __forceinline__ unsigned short f2bf(float f) {
    unsigned int u = __float_as_uint(f);
    return (unsigned short)((u + 0x7FFFu + ((u >> 16) & 1u)) >> 16);
}
__device__ __forceinline__ float bf2f(unsigned short u) {
    return __uint_as_float(((unsigned int)u) << 16);
}
__device__ __forceinline__ void split2(float f, unsigned short& hi, unsigned short& lo) {
    hi = f2bf(f);
    lo = f2bf(f - bf2f(hi));
}
// ---- truncation split (hot path): hi=trunc16(f), lo=trunc16(f-hi). ~4 VALU.
// Split error <= 2^-16 * |f| (same order as rne split; cheap).
__device__ __forceinline__ void splitT(float f, unsigned short& hi, unsigned short& lo) {
    unsigned int u  = __float_as_uint(f);
    unsigned int hb = u & 0xFFFF0000u;
    float l = f - __uint_as_float(hb);
    hi = (unsigned short)(u >> 16);
    lo = (unsigned short)(__float_as_uint(l) >> 16);
}
// ---- transcendentals without v_div (v_rcp_f32 is 1 instr, ~1ulp) ----
__device__ __forceinline__ float sigf(float x) {
    return __builtin_amdgcn_rcpf(1.0f + __expf(-x));
}
__device__ __forceinline__ float tanhfast(float x) {
    float cx = fminf(fmaxf(x, -15.0f), 15.0f);
    float e = __expf(2.0f * cx);
    return (e - 1.0f) * __builtin_amdgcn_rcpf(e + 1.0f);
}
// lane^8 exchange via DPP row_ror:8 (lane^8 within 16-lane rows)
__device__ __forceinline__ float xor8(float v) {
    return __builtin_bit_cast(float, __builtin_amdgcn_update_dpp(
        0, __builtin_bit_cast(int, v), 0x128, 0xF, 0xF, true));
}

#define MFMA16(A, B, C) __builtin_amdgcn_mfma_f32_16x16x32_bf16(A, B, C, 0, 0, 0)
#define BC8(x) __builtin_bit_cast(bf16x8, x)

// Raw workgroup barrier: LDS-only wait (no vmcnt drain -> global prefetch
// loads stay in flight across steps). Proven in R4.
#define BARRIER() do {                                        \
    asm volatile("s_waitcnt lgkmcnt(0)" ::: "memory");        \
    __builtin_amdgcn_s_barrier();                             \
    __builtin_amdgcn_sched_barrier(0);                        \
} while (0)

#define HS2 72    // hbuf row stride (u16): h_hi[0..31] h_lo[32..63] pad
#define MS  136   // mlps/hids row stride (u16): cat_hi[0..63] cat_lo[64..127]
#define XS2 136   // xbuf row stride (u16): x_hi[0..63] x_lo[64..127]

// 4 waves / 16 batch rows / block; grid 256. bf16 hi/lo GEMMs (fp32-grade).
// Encoder: x@K for step t+1 precomputed during step t (h-critical path =
// ds_read h + 3 MFMA + gates). Gates in C/D layout via DPP xor8. h double-
// buffered in LDS. Norms folded into weights/biases. rcp-based sigmoid/tanh.
__global__ __launch_bounds__(256) void tutina_kernel(
    const float* __restrict__ history, const float* __restrict__ control,
    const float* __restrict__ forecasts,
    const float* __restrict__ h_mean, const float* __restrict__ h_var,
    const float* __restrict__ c_mean, const float* __restrict__ c_var,
    const float* __restrict__ f_mean, const float* __restrict__ f_var,
    const float* __restrict__ conv_w, const float* __restrict__ conv_b,
    const float* __restrict__ lstm_k, const float* __restrict__ lstm_rk,
    const float* __restrict__ lstm_b,
    const float* __restrict__ w1, const float* __restrict__ b1,
    const float* __restrict__ w2, const float* __restrict__ b2,
    float* __restrict__ out)
{
    __shared__ unsigned short hbuf[2][16 * HS2];  // h transpose, ping-pong
    __shared__ unsigned short xbuf[16 * XS2];     // decoder xn staging
    __shared__ unsigned short mlps[16 * MS];      // MLP cat staging
    __shared__ unsigned short hids[16 * MS];      // MLP hidden staging
    __shared__ unsigned int   fcs[48 * 64];       // fc conv, packed (hi<<16)|lo

    const int tid  = threadIdx.x;
    const int lane = tid & 63;
    const int wid  = tid >> 6;
    const int l15  = lane & 15;
    const int l4   = lane >> 4;
    const int b0   = blockIdx.x * 16;

    // ---- zero h (t=0 state) and mlps (pad cols) ----
    for (int i = tid; i < 16 * HS2; i += 256) hbuf[0][i] = 0;
    for (int i = tid; i < 16 * MS;  i += 256) mlps[i] = 0;

    // ---- gate-interleaved z-column assignment (proven R2-R4) ----
    const int  uu     = l15 & 7;
    const bool lohalf = (l15 < 8);
    const int  u      = wid * 8 + uu;
    const int  jz0    = lohalf ? u      : 32 + u;
    const int  jz1    = lohalf ? 64 + u : 96 + u;
    const int  j1     = wid * 16 + l15;

    // ---- weight fragments (hi/lo rne), x-norm folded into K ----
    auto bfragK = [&](int kbase, int j, float& dacc, bf16x8& H, bf16x8& L) {
        u16x8 h, l;
#pragma unroll
        for (int i = 0; i < 8; i++) {
            int k = kbase + l4 * 8 + i;
            float sv = 1.0f / fmaxf(sqrtf(h_var[k]), EPSV);
            float w  = lstm_k[k * 128 + j] * sv;
            dacc += h_mean[k] * w;
            unsigned short hh, ll; split2(w, hh, ll);
            h[i] = hh; l[i] = ll;
        }
        H = BC8(h); L = BC8(l);
    };
    auto bfragP = [&](const float* W, int ldw, int kbase, int j, bf16x8& H, bf16x8& L) {
        u16x8 h, l;
#pragma unroll
        for (int i = 0; i < 8; i++) {
            int k = kbase + l4 * 8 + i;
            float w = W[k * ldw + j];
            unsigned short hh, ll; split2(w, hh, ll);
            h[i] = hh; l[i] = ll;
        }
        H = BC8(h); L = BC8(l);
    };
    auto bfragW11 = [&](int j, float& dacc, bf16x8& H, bf16x8& L) {
        u16x8 h, l;
#pragma unroll
        for (int i = 0; i < 8; i++) {
            int k = 32 + l4 * 8 + i;
            float w = 0.0f;
            if (k < 52) {
                w = w1[k * 64 + j];
                if (k < 48) {
                    float sv = 1.0f / fmaxf(sqrtf(c_var[k - 32]), EPSV);
                    w *= sv;
                    dacc += c_mean[k - 32] * w;
                }
            }
            unsigned short hh, ll; split2(w, hh, ll);
            h[i] = hh; l[i] = ll;
        }
        H = BC8(h); L = BC8(l);
    };

    bf16x8 fA0h, fA0l, fA1h, fA1l, fA2h, fA2l;
    bf16x8 fB0h, fB0l, fB1h, fB1l, fB2h, fB2l;
    bf16x8 fW10h, fW10l, fW11h, fW11l, fW20h, fW20l, fW21h, fW21l;
    float dz0 = 0.f, dz1 = 0.f, d1 = 0.f;
    bfragK(0,  jz0, dz0, fA0h, fA0l);
    bfragK(32, jz0, dz0, fA1h, fA1l);
    bfragP(lstm_rk, 128, 0, jz0, fA2h, fA2l);
    bfragK(0,  jz1, dz1, fB0h, fB0l);
    bfragK(32, jz1, dz1, fB1h, fB1l);
    bfragP(lstm_rk, 128, 0, jz1, fB2h, fB2l);
    bfragP(w1, 64, 0, j1, fW10h, fW10l);
    bfragW11(j1, d1, fW11h, fW11l);
    bfragP(w2, 64, 0,  j1, fW20h, fW20l);
    bfragP(w2, 64, 32, j1, fW21h, fW21l);

    dz0 += __shfl_xor(dz0, 16, 64); dz0 += __shfl_xor(dz0, 32, 64);
    dz1 += __shfl_xor(dz1, 16, 64); dz1 += __shfl_xor(dz1, 32, 64);
    d1  += __shfl_xor(d1, 16, 64);  d1  += __shfl_xor(d1, 32, 64);
    float pd0 = xor8(dz0), pd1 = xor8(dz1);
    const float bi_ = lstm_b[u]      - (lohalf ? dz0 : pd0);
    const float bf_ = lstm_b[32 + u] - (lohalf ? pd0 : dz0);
    const float bg_ = lstm_b[64 + u] - (lohalf ? dz1 : pd1);
    const float bo_ = lstm_b[96 + u] - (lohalf ? pd1 : dz1);
    const float b1j = b1[j1] - d1;
    const float b2j = b2[j1];

    const int r0 = l4 * 4 + (lohalf ? 0 : 2);
    const int r1 = r0 + 1;
    float c0 = 0.0f, c1 = 0.0f;

    // cn staging mapping (threads 0..63)
    const int rc = tid >> 2, cc = (tid & 3) * 4;

    // ---- fc conv precompute: packed (hi<<16)|lo, rne ----
    {
        float fm  = f_mean[0];
        float fsc = 1.0f / fmaxf(sqrtf(f_var[0]), EPSV);
        for (int cell = tid; cell < 48 * 64; cell += 256) {
            int t  = cell >> 6;
            int b  = (cell >> 2) & 15;
            int uc = cell & 3;
            const float* fp = forecasts + ((size_t)(b0 + b) * 49 + t) * 8;
            float acc = conv_b[uc];
#pragma unroll
            for (int k = 0; k < 8; k++) {
                acc += (fp[k]     - fm) * fsc * conv_w[k * 4 + uc];
                acc += (fp[8 + k] - fm) * fsc * conv_w[32 + k * 4 + uc];
            }
            unsigned short hh, ll; split2(acc, hh, ll);
            fcs[cell] = ((unsigned int)hh << 16) | ll;
        }
    }

    // ---- gates in C/D layout (DPP xor8); writes h to hw (+ mlps.h opt) ----
    auto lstm_gates = [&](const f32x4& a, const f32x4& b,
                          unsigned short* hw, bool write_mlp) {
        float sa0 = lohalf ? a[2] : a[0];
        float sa1 = lohalf ? a[3] : a[1];
        float sb0 = lohalf ? b[2] : b[0];
        float sb1 = lohalf ? b[3] : b[1];
        float ra0 = xor8(sa0);
        float ra1 = xor8(sa1);
        float rb0 = xor8(sb0);
        float rb1 = xor8(sb1);
        float zi0 = (lohalf ? a[0] : ra0) + bi_;
        float zi1 = (lohalf ? a[1] : ra1) + bi_;
        float zf0 = (lohalf ? ra0 : a[2]) + bf_;
        float zf1 = (lohalf ? ra1 : a[3]) + bf_;
        float zg0 = (lohalf ? b[0] : rb0) + bg_;
        float zg1 = (lohalf ? b[1] : rb1) + bg_;
        float zo0 = (lohalf ? rb0 : b[2]) + bo_;
        float zo1 = (lohalf ? rb1 : b[3]) + bo_;
        c0 = sigf(zf0) * c0 + sigf(zi0) * tanhfast(zg0);
        c1 = sigf(zf1) * c1 + sigf(zi1) * tanhfast(zg1);
        float h20 = sigf(zo0) * tanhfast(c0);
        float h21 = sigf(zo1) * tanhfast(c1);
        unsigned short bh, bl;
        splitT(h20, bh, bl);
        hw[r0 * HS2 + u]      = bh;
        hw[r0 * HS2 + 32 + u] = bl;
        if (write_mlp) { mlps[r0 * MS + u] = bh; mlps[r0 * MS + 64 + u] = bl; }
        splitT(h21, bh, bl);
        hw[r1 * HS2 + u]      = bh;
        hw[r1 * HS2 + 32 + u] = bl;
        if (write_mlp) { mlps[r1 * MS + u] = bh; mlps[r1 * MS + 64 + u] = bl; }
    };

    // ---- encoder prologue: x_0 -> zx, x_1 -> regs ----
    const float* hp = history + (size_t)(b0 + l15) * (168 * 64);
    const int o1 = l4 * 8, o2 = 32 + l4 * 8;

    auto mk_frags = [&](const f32x4& p0, const f32x4& p1, const f32x4& p2,
                        const f32x4& p3, bf16x8& A0h, bf16x8& A0l,
                        bf16x8& A1h, bf16x8& A1l) {
        u16x8 xh_, xl_;
        unsigned short hh, ll;
#pragma unroll
        for (int i = 0; i < 4; i++) { splitT(p0[i], hh, ll); xh_[i] = hh; xl_[i] = ll; }
#pragma unroll
        for (int i = 0; i < 4; i++) { splitT(p1[i], hh, ll); xh_[4+i] = hh; xl_[4+i] = ll; }
        A0h = BC8(xh_); A0l = BC8(xl_);
#pragma unroll
        for (int i = 0; i < 4; i++) { splitT(p2[i], hh, ll); xh_[i] = hh; xl_[i] = ll; }
#pragma unroll
        for (int i = 0; i < 4; i++) { splitT(p3[i], hh, ll); xh_[4+i] = hh; xl_[4+i] = ll; }
        A1h = BC8(xh_); A1l = BC8(xl_);
    };
    auto zx12 = [&](bf16x8 A0h, bf16x8 A0l, bf16x8 A1h, bf16x8 A1l,
                    f32x4& zn0, f32x4& zn1) {
        f32x4 s0 = {0.f,0.f,0.f,0.f}, s1 = {0.f,0.f,0.f,0.f};
        s0 = MFMA16(A0h, fA0h, s0);  s1 = MFMA16(A0h, fB0h, s1);
        s0 = MFMA16(A1h, fA1h, s0);  s1 = MFMA16(A1h, fB1h, s1);
        s0 = MFMA16(A0l, fA0h, s0);  s1 = MFMA16(A0l, fB0h, s1);
        s0 = MFMA16(A1l, fA1h, s0);  s1 = MFMA16(A1l, fB1h, s1);
        s0 = MFMA16(A0h, fA0l, s0);  s1 = MFMA16(A0h, fB0l, s1);
        s0 = MFMA16(A1h, fA1l, s0);  s1 = MFMA16(A1h, fB1l, s1);
        zn0 = s0; zn1 = s1;
    };

    f32x4 zx0, zx1;
    {
        f32x4 p0 = *(const f32x4*)(hp + o1), p1 = *(const f32x4*)(hp + o1 + 4);
        f32x4 p2 = *(const f32x4*)(hp + o2), p3 = *(const f32x4*)(hp + o2 + 4);
        bf16x8 A0h, A0l, A1h, A1l;
        mk_frags(p0, p1, p2, p3, A0h, A0l, A1h, A1l);
        zx12(A0h, A0l, A1h, A1l, zx0, zx1);
    }
    f32x4 vb0 = *(const f32x4*)(hp + 64 + o1), vb1 = *(const f32x4*)(hp + 64 + o1 + 4);
    f32x4 vb2 = *(const f32x4*)(hp + 64 + o2), vb3 = *(const f32x4*)(hp + 64 + o2 + 4);

    BARRIER();   // zero-init + fcs visible

    // ---- encoder: 168 steps, 1 barrier each ----
    for (int t = 0; t < 168; ++t) {
        const int p = t & 1;
        // h_t fragments (critical path head)
        const unsigned short* hr = hbuf[p];
        bf16x8 a2h = BC8(*(const u32x4*)&hr[l15 * HS2 + l4 * 8]);
        bf16x8 a2l = BC8(*(const u32x4*)&hr[l15 * HS2 + 32 + l4 * 8]);

        // x_{t+1}: split regs -> frags; prefetch x_{t+2}
        bf16x8 A0h, A0l, A1h, A1l;
        mk_frags(vb0, vb1, vb2, vb3, A0h, A0l, A1h, A1l);
        const float* np = hp + (size_t)((t < 166) ? t + 2 : 167) * 64;
        vb0 = *(const f32x4*)(np + o1); vb1 = *(const f32x4*)(np + o1 + 4);
        vb2 = *(const f32x4*)(np + o2); vb3 = *(const f32x4*)(np + o2 + 4);

        // off-critical: zx for t+1
        f32x4 zn0, zn1;
        zx12(A0h, A0l, A1h, A1l, zn0, zn1);

        // critical: finish z_t with recurrent terms (depth 3)
        f32x4 z0 = zx0, z1 = zx1;
        z0 = MFMA16(a2h, fA2h, z0);  z1 = MFMA16(a2h, fB2h, z1);
        z0 = MFMA16(a2l, fA2h, z0);  z1 = MFMA16(a2l, fB2h, z1);
        z0 = MFMA16(a2h, fA2l, z0);  z1 = MFMA16(a2h, fB2l, z1);

        lstm_gates(z0, z1, hbuf[p ^ 1], t == 167);
        BARRIER();
        zx0 = zn0; zx1 = zn1;
    }
    // h_168 in hbuf[0] and mlps.h

    // ---- latest + control slice 0 ----
    float lat0 = history[((size_t)(b0 + l4 * 4 + 0) * 168 + 167) * 64 + j1];
    float lat1 = history[((size_t)(b0 + l4 * 4 + 1) * 168 + 167) * 64 + j1];
    float lat2 = history[((size_t)(b0 + l4 * 4 + 2) * 168 + 167) * 64 + j1];
    float lat3 = history[((size_t)(b0 + l4 * 4 + 3) * 168 + 167) * 64 + j1];
    f32x4 creg = {0.f, 0.f, 0.f, 0.f};
    if (tid < 64)
        creg = *(const f32x4*)(control + ((size_t)(b0 + rc) * 48 + 0) * 16 + cc);

    auto stage_cn = [&](const f32x4& v) {
        if (tid < 64) {
            u16x4 oh, ol;
#pragma unroll
            for (int q = 0; q < 4; q++) {
                unsigned short hh, ll;
                splitT(v[q], hh, ll);
                oh[q] = hh; ol[q] = ll;
            }
            *(u16x4*)&mlps[rc * MS + 32 + cc]      = oh;
            *(u16x4*)&mlps[rc * MS + 64 + 32 + cc] = ol;
        }
    };
    auto stage_fc = [&](int t) {
        if (tid >= 64 && tid < 128) {
            int q = tid - 64;
            unsigned int v = fcs[t * 64 + q];
            mlps[(q >> 2) * MS + 48 + (q & 3)]      = (unsigned short)(v >> 16);
            mlps[(q >> 2) * MS + 64 + 48 + (q & 3)] = (unsigned short)(v & 0xFFFFu);
        }
    };

    auto mlp1 = [&]() {
        const int mbase = l15 * MS + l4 * 8;
        bf16x8 m0  = BC8(*(const u32x4*)&mlps[mbase]);
        bf16x8 m1  = BC8(*(const u32x4*)&mlps[mbase + 32]);
        bf16x8 m0l = BC8(*(const u32x4*)&mlps[mbase + 64]);
        bf16x8 m1l = BC8(*(const u32x4*)&mlps[mbase + 96]);
        f32x4 ha = {0.f,0.f,0.f,0.f}, hb = {0.f,0.f,0.f,0.f};
        ha = MFMA16(m0,  fW10h, ha);   hb = MFMA16(m1,  fW11h, hb);
        ha = MFMA16(m0l, fW10h, ha);   hb = MFMA16(m1l, fW11h, hb);
        ha = MFMA16(m0,  fW10l, ha);   hb = MFMA16(m1,  fW11l, hb);
        f32x4 hacc = ha + hb;
#pragma unroll
        for (int q = 0; q < 4; q++) {
            float hv = fmaxf(hacc[q] + b1j, 0.0f);
            unsigned short hh, ll;
            splitT(hv, hh, ll);
            hids[(l4 * 4 + q) * MS + j1]      = hh;
            hids[(l4 * 4 + q) * MS + 64 + j1] = ll;
        }
    };
    auto mlp2 = [&]() {
        const int mbase = l15 * MS + l4 * 8;
        bf16x8 h0  = BC8(*(const u32x4*)&hids[mbase]);
        bf16x8 h1  = BC8(*(const u32x4*)&hids[mbase + 32]);
        bf16x8 h0l = BC8(*(const u32x4*)&hids[mbase + 64]);
        bf16x8 h1l = BC8(*(const u32x4*)&hids[mbase + 96]);
        f32x4 oa = {0.f,0.f,0.f,0.f}, ob = {0.f,0.f,0.f,0.f};
        oa = MFMA16(h0,  fW20h, oa);   ob = MFMA16(h1,  fW21h, ob);
        oa = MFMA16(h0l, fW20h, oa);   ob = MFMA16(h1l, fW21h, ob);
        oa = MFMA16(h0,  fW20l, oa);   ob = MFMA16(h1,  fW21l, ob);
        f32x4 oacc = oa + ob;
        lat0 += oacc[0] + b2j;
        lat1 += oacc[1] + b2j;
        lat2 += oacc[2] + b2j;
        lat3 += oacc[3] + b2j;
    };

    // ---- post-encoder MLP ----
    stage_cn(creg);
    stage_fc(0);
    BARRIER();
    mlp1();
    BARRIER();
    mlp2();

    // ---- decoder: 48 steps, 3 barriers each ----
    for (int t = 0; t < 48; ++t) {
        const int p = t & 1;
        // phase 1: xn (raw; norm folded) -> xbuf ; cn/fc -> mlps
        unsigned short bh, bl;
        splitT(lat0, bh, bl);
        xbuf[(l4 * 4 + 0) * XS2 + j1] = bh; xbuf[(l4 * 4 + 0) * XS2 + 64 + j1] = bl;
        splitT(lat1, bh, bl);
        xbuf[(l4 * 4 + 1) * XS2 + j1] = bh; xbuf[(l4 * 4 + 1) * XS2 + 64 + j1] = bl;
        splitT(lat2, bh, bl);
        xbuf[(l4 * 4 + 2) * XS2 + j1] = bh; xbuf[(l4 * 4 + 2) * XS2 + 64 + j1] = bl;
        splitT(lat3, bh, bl);
        xbuf[(l4 * 4 + 3) * XS2 + j1] = bh; xbuf[(l4 * 4 + 3) * XS2 + 64 + j1] = bl;
        stage_cn(creg);
        stage_fc(t);
        int tn = (t < 47) ? t + 1 : 47;
        if (tid < 64)
            creg = *(const f32x4*)(control + ((size_t)(b0 + rc) * 48 + tn) * 16 + cc);
        BARRIER();   // B1

        // phase 2: full 18-MFMA z GEMM + gates
        const unsigned short* hr = hbuf[p];
        const int xb = l15 * XS2 + l4 * 8;
        bf16x8 a0h = BC8(*(const u32x4*)&xbuf[xb]);
        bf16x8 a1h = BC8(*(const u32x4*)&xbuf[xb + 32]);
        bf16x8 a0l = BC8(*(const u32x4*)&xbuf[xb + 64]);
        bf16x8 a1l = BC8(*(const u32x4*)&xbuf[xb + 96]);
        bf16x8 a2h = BC8(*(const u32x4*)&hr[l15 * HS2 + l4 * 8]);
        bf16x8 a2l = BC8(*(const u32x4*)&hr[l15 * HS2 + 32 + l4 * 8]);
        f32x4 z0a = {0.f,0.f,0.f,0.f}, z0b = {0.f,0.f,0.f,0.f};
        f32x4 z1a = {0.f,0.f,0.f,0.f}, z1b = {0.f,0.f,0.f,0.f};
        z0a = MFMA16(a0h, fA0h, z0a);  z1a = MFMA16(a0h, fB0h, z1a);
        z0b = MFMA16(a1h, fA1h, z0b);  z1b = MFMA16(a1h, fB1h, z1b);
        z0a = MFMA16(a2h, fA2h, z0a);  z1a = MFMA16(a2h, fB2h, z1a);
        z0b = MFMA16(a0l, fA0h, z0b);  z1b = MFMA16(a0l, fB0h, z1b);
        z0a = MFMA16(a1l, fA1h, z0a);  z1a = MFMA16(a1l, fB1h, z1a);
        z0b = MFMA16(a2l, fA2h, z0b);  z1b = MFMA16(a2l, fB2h, z1b);
        z0a = MFMA16(a0h, fA0l, z0a);  z1a = MFMA16(a0h, fB0l, z1a);
        z0b = MFMA16(a1h, fA1l, z0b);  z1b = MFMA16(a1h, fB1l, z1b);
        z0a = MFMA16(a2h, fA2l, z0a);  z1a = MFMA16(a2h, fB2l, z1a);
        f32x4 z0 = z0a + z0b, z1 = z1a + z1b;
        lstm_gates(z0, z1, hbuf[p ^ 1], true);
        BARRIER();   // B2

        // phase 3: MLP
        mlp1();
        BARRIER();   // B3
        mlp2();

        out[((size_t)(b0 + l4 * 4 + 0) * 48 + t) * 64 + j1] = lat0;
        out[((size_t)(b0 + l4 * 4 + 1) * 48 + t) * 64 + j1] = lat1;
        out[((size_t)(b0 + l4 * 4 + 2) * 48 + t) * 64 + j1] = lat2;
        out[((size_t)(b0 + l4 * 4 + 3) * 48 + t) * 64 + j1] = lat3;
    }
}

extern "C" void kernel_launch(void* const* d_in, const int* in_sizes, int n_in,
                              void* d_out, int out_size, void* d_ws, size_t ws_size,
                              hipStream_t stream) {
    tutina_kernel<<<dim3(256), dim3(256), 0, stream>>>(
        (const float*)d_in[0],  (const float*)d_in[1],  (const float*)d_in[2],
        (const float*)d_in[3],  (const float*)d_in[4],  (const float*)d_in[5],
        (const float*)d_in[6],  (const float*)d_in[7],  (const float*)d_in[8],
        (const float*)d_in[9],  (const float*)d_in[10], (const float*)d_in[11],
        (const float*)d_in[12], (const float*)d_in[13], (const float*)d_in[14],
        (const float*)d_in[15], (const float*)d_in[16], (const float*)d_in[17],
        (float*)d_out);
}

// Round 8
// 169.961 us; speedup vs baseline: 3.6045x; 1.0951x over previous
//
#include <hip/hip_runtime.h>

#define EPSV 1e-7f

typedef __bf16 bf16x8 __attribute__((ext_vector_type(8)));
typedef float  f32x4  __attribute__((ext_vector_type(4)));
typedef unsigned int   u32x4 __attribute__((ext_vector_type(4)));
typedef unsigned short u16x8 __attribute__((ext_vector_type(8)));
typedef unsigned short u16x4 __attribute__((ext_vector_type(4)));

// ---- rne bf16 (setup paths) ----
__device__ __forceinline__ unsigned short f2bf(float f) {
    unsigned int u = __float_as_uint(f);
    return (unsigned short)((u + 0x7FFFu + ((u >> 16) & 1u)) >> 16);
}
__device__ __forceinline__ float bf2f(unsigned short u) {
    return __uint_as_float(((unsigned int)u) << 16);
}
__device__ __forceinline__ void split2(float f, unsigned short& hi, unsigned short& lo) {
    hi = f2bf(f);
    lo = f2bf(f - bf2f(hi));
}
// ---- truncation split (hot path) ----
__device__ __forceinline__ void splitT(float f, unsigned short& hi, unsigned short& lo) {
    unsigned int u  = __float_as_uint(f);
    unsigned int hb = u & 0xFFFF0000u;
    float l = f - __uint_as_float(hb);
    hi = (unsigned short)(u >> 16);
    lo = (unsigned short)(__float_as_uint(l) >> 16);
}
__device__ __forceinline__ float sigf(float x) {
    return __builtin_amdgcn_rcpf(1.0f + __expf(-x));
}
__device__ __forceinline__ float tanhfast(float x) {
    float cx = fminf(fmaxf(x, -15.0f), 15.0f);
    float e = __expf(2.0f * cx);
    return (e - 1.0f) * __builtin_amdgcn_rcpf(e + 1.0f);
}
__device__ __forceinline__ float xor8(float v) {
    return __builtin_bit_cast(float, __builtin_amdgcn_update_dpp(
        0, __builtin_bit_cast(int, v), 0x128, 0xF, 0xF, true));
}

#define MFMA16(A, B, C) __builtin_amdgcn_mfma_f32_16x16x32_bf16(A, B, C, 0, 0, 0)
#define BC8(x) __builtin_bit_cast(bf16x8, x)

// LDS-only workgroup barrier (no vmcnt drain; prefetch floats across)
#define BARRIER() do {                                        \
    asm volatile("s_waitcnt lgkmcnt(0)" ::: "memory");        \
    __builtin_amdgcn_s_barrier();                             \
    __builtin_amdgcn_sched_barrier(0);                        \
} while (0)

#define HS2 72    // hbuf row stride (u16): h_hi[0..31] h_lo[32..63] pad
#define MS  136   // mlps/hids row stride (u16)
#define XS2 136   // xbuf row stride (u16)
#define ZS3 20    // zx col stride (f32): 16 rows + 4 pad (2-way banks)

// 512 threads = 8 waves, 16 batch rows, grid 256 -> 2 waves/SIMD.
// Waves 0-3 (A): recurrent critical path (zx + h@R -> gates -> h).
// Waves 4-7 (B): x@K producer (encoder) / staging + MLP + latest (decoder).
__global__ __launch_bounds__(512, 1) void tutina_kernel(
    const float* __restrict__ history, const float* __restrict__ control,
    const float* __restrict__ forecasts,
    const float* __restrict__ h_mean, const float* __restrict__ h_var,
    const float* __restrict__ c_mean, const float* __restrict__ c_var,
    const float* __restrict__ f_mean, const float* __restrict__ f_var,
    const float* __restrict__ conv_w, const float* __restrict__ conv_b,
    const float* __restrict__ lstm_k, const float* __restrict__ lstm_rk,
    const float* __restrict__ lstm_b,
    const float* __restrict__ w1, const float* __restrict__ b1,
    const float* __restrict__ w2, const float* __restrict__ b2,
    float* __restrict__ out)
{
    __shared__ unsigned short hbuf[2][16 * HS2];   // h, ping-pong
    __shared__ float zxb[2][4][2][16 * ZS3];       // x@K partials, ping-pong
    __shared__ unsigned short xbuf[16 * XS2];      // decoder xn staging
    __shared__ unsigned short mlps[16 * MS];       // MLP cat staging
    __shared__ unsigned short hids[16 * MS];       // MLP hidden staging
    __shared__ unsigned int   fcs[48 * 64];        // fc conv, packed (hi<<16)|lo

    const int tid  = threadIdx.x;
    const int lane = tid & 63;
    const int wid  = tid >> 6;      // 0..7
    const int wa   = wid & 3;       // role-local wave index
    const bool gA  = (wid < 4);
    const int lt   = tid & 255;     // group-local thread id
    const int l15  = lane & 15;
    const int l4   = lane >> 4;
    const int b0   = blockIdx.x * 16;

    for (int i = tid; i < 16 * HS2; i += 512) hbuf[0][i] = 0;
    for (int i = tid; i < 16 * MS;  i += 512) mlps[i] = 0;

    const int  uu     = l15 & 7;
    const bool lohalf = (l15 < 8);
    const int  u      = wa * 8 + uu;
    const int  jz0    = lohalf ? u      : 32 + u;
    const int  jz1    = lohalf ? 64 + u : 96 + u;
    const int  j1     = wa * 16 + l15;

    // ---- fragment builders ----
    auto bfragK = [&](int kbase, int j, float& dacc, bf16x8& H, bf16x8& L) {
        u16x8 h, l;
#pragma unroll
        for (int i = 0; i < 8; i++) {
            int k = kbase + l4 * 8 + i;
            float sv = 1.0f / fmaxf(sqrtf(h_var[k]), EPSV);
            float w  = lstm_k[k * 128 + j] * sv;
            dacc += h_mean[k] * w;
            unsigned short hh, ll; split2(w, hh, ll);
            h[i] = hh; l[i] = ll;
        }
        H = BC8(h); L = BC8(l);
    };
    auto bfragP = [&](const float* W, int ldw, int kbase, int j, bf16x8& H, bf16x8& L) {
        u16x8 h, l;
#pragma unroll
        for (int i = 0; i < 8; i++) {
            int k = kbase + l4 * 8 + i;
            float w = W[k * ldw + j];
            unsigned short hh, ll; split2(w, hh, ll);
            h[i] = hh; l[i] = ll;
        }
        H = BC8(h); L = BC8(l);
    };
    auto bfragW11 = [&](int j, float& dacc, bf16x8& H, bf16x8& L) {
        u16x8 h, l;
#pragma unroll
        for (int i = 0; i < 8; i++) {
            int k = 32 + l4 * 8 + i;
            float w = 0.0f;
            if (k < 52) {
                w = w1[k * 64 + j];
                if (k < 48) {
                    float sv = 1.0f / fmaxf(sqrtf(c_var[k - 32]), EPSV);
                    w *= sv;
                    dacc += c_mean[k - 32] * w;
                }
            }
            unsigned short hh, ll; split2(w, hh, ll);
            h[i] = hh; l[i] = ll;
        }
        H = BC8(h); L = BC8(l);
    };

    // ---- K x-frags (both groups; B computes zx, A uses them in decoder) ----
    bf16x8 fA0h, fA0l, fA1h, fA1l, fB0h, fB0l, fB1h, fB1l;
    float dz0 = 0.f, dz1 = 0.f;
    bfragK(0,  jz0, dz0, fA0h, fA0l);
    bfragK(32, jz0, dz0, fA1h, fA1l);
    bfragK(0,  jz1, dz1, fB0h, fB0l);
    bfragK(32, jz1, dz1, fB1h, fB1l);

    // ---- A: recurrent frags + gate biases ----
    bf16x8 fA2h, fA2l, fB2h, fB2l;
    float bi_ = 0.f, bf_ = 0.f, bg_ = 0.f, bo_ = 0.f;
    if (gA) {
        bfragP(lstm_rk, 128, 0, jz0, fA2h, fA2l);
        bfragP(lstm_rk, 128, 0, jz1, fB2h, fB2l);
        float z0s = dz0, z1s = dz1;
        z0s += __shfl_xor(z0s, 16, 64); z0s += __shfl_xor(z0s, 32, 64);
        z1s += __shfl_xor(z1s, 16, 64); z1s += __shfl_xor(z1s, 32, 64);
        float pd0 = xor8(z0s), pd1 = xor8(z1s);
        bi_ = lstm_b[u]      - (lohalf ? z0s : pd0);
        bf_ = lstm_b[32 + u] - (lohalf ? pd0 : z0s);
        bg_ = lstm_b[64 + u] - (lohalf ? z1s : pd1);
        bo_ = lstm_b[96 + u] - (lohalf ? pd1 : z1s);
    }

    // ---- B: MLP frags, latest, control, fc conv ----
    bf16x8 fW10h, fW10l, fW11h, fW11l, fW20h, fW20l, fW21h, fW21l;
    float b1j = 0.f, b2j = 0.f;
    float lat0 = 0.f, lat1 = 0.f, lat2 = 0.f, lat3 = 0.f;
    f32x4 creg = {0.f, 0.f, 0.f, 0.f};
    const int rc = lt >> 2, cc = (lt & 3) * 4;
    if (!gA) {
        bfragP(w1, 64, 0, j1, fW10h, fW10l);
        float d1 = 0.f;
        bfragW11(j1, d1, fW11h, fW11l);
        bfragP(w2, 64, 0,  j1, fW20h, fW20l);
        bfragP(w2, 64, 32, j1, fW21h, fW21l);
        d1 += __shfl_xor(d1, 16, 64); d1 += __shfl_xor(d1, 32, 64);
        b1j = b1[j1] - d1;
        b2j = b2[j1];
        lat0 = history[((size_t)(b0 + l4 * 4 + 0) * 168 + 167) * 64 + j1];
        lat1 = history[((size_t)(b0 + l4 * 4 + 1) * 168 + 167) * 64 + j1];
        lat2 = history[((size_t)(b0 + l4 * 4 + 2) * 168 + 167) * 64 + j1];
        lat3 = history[((size_t)(b0 + l4 * 4 + 3) * 168 + 167) * 64 + j1];
        if (lt < 64)
            creg = *(const f32x4*)(control + ((size_t)(b0 + rc) * 48 + 0) * 16 + cc);
        float fm  = f_mean[0];
        float fsc = 1.0f / fmaxf(sqrtf(f_var[0]), EPSV);
        for (int cell = lt; cell < 48 * 64; cell += 256) {
            int t  = cell >> 6;
            int b  = (cell >> 2) & 15;
            int uc = cell & 3;
            const float* fp = forecasts + ((size_t)(b0 + b) * 49 + t) * 8;
            float acc = conv_b[uc];
#pragma unroll
            for (int k = 0; k < 8; k++) {
                acc += (fp[k]     - fm) * fsc * conv_w[k * 4 + uc];
                acc += (fp[8 + k] - fm) * fsc * conv_w[32 + k * 4 + uc];
            }
            unsigned short hh, ll; split2(acc, hh, ll);
            fcs[cell] = ((unsigned int)hh << 16) | ll;
        }
    }

    const int r0 = l4 * 4 + (lohalf ? 0 : 2);
    const int r1 = r0 + 1;
    float c0 = 0.0f, c1 = 0.0f;

    // ---- gates (A): DPP xor8 exchange; write h ----
    auto lstm_gates = [&](const f32x4& a, const f32x4& b,
                          unsigned short* hw, bool write_mlp) {
        float sa0 = lohalf ? a[2] : a[0];
        float sa1 = lohalf ? a[3] : a[1];
        float sb0 = lohalf ? b[2] : b[0];
        float sb1 = lohalf ? b[3] : b[1];
        float ra0 = xor8(sa0);
        float ra1 = xor8(sa1);
        float rb0 = xor8(sb0);
        float rb1 = xor8(sb1);
        float zi0 = (lohalf ? a[0] : ra0) + bi_;
        float zi1 = (lohalf ? a[1] : ra1) + bi_;
        float zf0 = (lohalf ? ra0 : a[2]) + bf_;
        float zf1 = (lohalf ? ra1 : a[3]) + bf_;
        float zg0 = (lohalf ? b[0] : rb0) + bg_;
        float zg1 = (lohalf ? b[1] : rb1) + bg_;
        float zo0 = (lohalf ? rb0 : b[2]) + bo_;
        float zo1 = (lohalf ? rb1 : b[3]) + bo_;
        c0 = sigf(zf0) * c0 + sigf(zi0) * tanhfast(zg0);
        c1 = sigf(zf1) * c1 + sigf(zi1) * tanhfast(zg1);
        float h20 = sigf(zo0) * tanhfast(c0);
        float h21 = sigf(zo1) * tanhfast(c1);
        unsigned short bh, bl;
        splitT(h20, bh, bl);
        hw[r0 * HS2 + u]      = bh;
        hw[r0 * HS2 + 32 + u] = bl;
        if (write_mlp) { mlps[r0 * MS + u] = bh; mlps[r0 * MS + 64 + u] = bl; }
        splitT(h21, bh, bl);
        hw[r1 * HS2 + u]      = bh;
        hw[r1 * HS2 + 32 + u] = bl;
        if (write_mlp) { mlps[r1 * MS + u] = bh; mlps[r1 * MS + 64 + u] = bl; }
    };

    // ---- B: x frags + x@K (12 MFMA) ----
    auto mk_frags = [&](const f32x4& p0, const f32x4& p1, const f32x4& p2,
                        const f32x4& p3, bf16x8& A0h, bf16x8& A0l,
                        bf16x8& A1h, bf16x8& A1l) {
        u16x8 xh_, xl_;
        unsigned short hh, ll;
#pragma unroll
        for (int i = 0; i < 4; i++) { splitT(p0[i], hh, ll); xh_[i] = hh; xl_[i] = ll; }
#pragma unroll
        for (int i = 0; i < 4; i++) { splitT(p1[i], hh, ll); xh_[4+i] = hh; xl_[4+i] = ll; }
        A0h = BC8(xh_); A0l = BC8(xl_);
#pragma unroll
        for (int i = 0; i < 4; i++) { splitT(p2[i], hh, ll); xh_[i] = hh; xl_[i] = ll; }
#pragma unroll
        for (int i = 0; i < 4; i++) { splitT(p3[i], hh, ll); xh_[4+i] = hh; xl_[4+i] = ll; }
        A1h = BC8(xh_); A1l = BC8(xl_);
    };
    auto zx12 = [&](bf16x8 A0h, bf16x8 A0l, bf16x8 A1h, bf16x8 A1l,
                    f32x4& zn0, f32x4& zn1) {
        f32x4 s0 = {0.f,0.f,0.f,0.f}, s1 = {0.f,0.f,0.f,0.f};
        s0 = MFMA16(A0h, fA0h, s0);  s1 = MFMA16(A0h, fB0h, s1);
        s0 = MFMA16(A1h, fA1h, s0);  s1 = MFMA16(A1h, fB1h, s1);
        s0 = MFMA16(A0l, fA0h, s0);  s1 = MFMA16(A0l, fB0h, s1);
        s0 = MFMA16(A1l, fA1h, s0);  s1 = MFMA16(A1l, fB1h, s1);
        s0 = MFMA16(A0h, fA0l, s0);  s1 = MFMA16(A0h, fB0l, s1);
        s0 = MFMA16(A1h, fA1l, s0);  s1 = MFMA16(A1h, fB1l, s1);
        zn0 = s0; zn1 = s1;
    };

    // ---- encoder prologue (B): zx[0], prefetch x_1 ----
    const float* hp = history + (size_t)(b0 + l15) * (168 * 64);
    const int o1 = l4 * 8, o2 = 32 + l4 * 8;
    const int zoff = l15 * ZS3 + l4 * 4;
    f32x4 vb0, vb1, vb2, vb3;
    if (!gA) {
        f32x4 p0 = *(const f32x4*)(hp + o1), p1 = *(const f32x4*)(hp + o1 + 4);
        f32x4 p2 = *(const f32x4*)(hp + o2), p3 = *(const f32x4*)(hp + o2 + 4);
        bf16x8 A0h, A0l, A1h, A1l;
        mk_frags(p0, p1, p2, p3, A0h, A0l, A1h, A1l);
        f32x4 zn0, zn1;
        zx12(A0h, A0l, A1h, A1l, zn0, zn1);
        *(f32x4*)&zxb[0][wa][0][zoff] = zn0;
        *(f32x4*)&zxb[0][wa][1][zoff] = zn1;
        vb0 = *(const f32x4*)(hp + 64 + o1); vb1 = *(const f32x4*)(hp + 64 + o1 + 4);
        vb2 = *(const f32x4*)(hp + 64 + o2); vb3 = *(const f32x4*)(hp + 64 + o2 + 4);
    }
    if (gA) __builtin_amdgcn_s_setprio(1);   // favor critical-path waves
    BARRIER();

    // ---- encoder: 168 steps, 1 barrier each ----
    for (int t = 0; t < 168; ++t) {
        const int p = t & 1;
        if (gA) {
            const unsigned short* hr = hbuf[p];
            bf16x8 a2h = BC8(*(const u32x4*)&hr[l15 * HS2 + l4 * 8]);
            bf16x8 a2l = BC8(*(const u32x4*)&hr[l15 * HS2 + 32 + l4 * 8]);
            f32x4 z0 = *(const f32x4*)&zxb[p][wa][0][zoff];
            f32x4 z1 = *(const f32x4*)&zxb[p][wa][1][zoff];
            z0 = MFMA16(a2h, fA2h, z0);  z1 = MFMA16(a2h, fB2h, z1);
            z0 = MFMA16(a2l, fA2h, z0);  z1 = MFMA16(a2l, fB2h, z1);
            z0 = MFMA16(a2h, fA2l, z0);  z1 = MFMA16(a2h, fB2l, z1);
            lstm_gates(z0, z1, hbuf[p ^ 1], t == 167);
        } else {
            bf16x8 A0h, A0l, A1h, A1l;
            mk_frags(vb0, vb1, vb2, vb3, A0h, A0l, A1h, A1l);
            const float* np = hp + (size_t)((t < 166) ? t + 2 : 167) * 64;
            vb0 = *(const f32x4*)(np + o1); vb1 = *(const f32x4*)(np + o1 + 4);
            vb2 = *(const f32x4*)(np + o2); vb3 = *(const f32x4*)(np + o2 + 4);
            f32x4 zn0, zn1;
            zx12(A0h, A0l, A1h, A1l, zn0, zn1);
            *(f32x4*)&zxb[p ^ 1][wa][0][zoff] = zn0;
            *(f32x4*)&zxb[p ^ 1][wa][1][zoff] = zn1;
        }
        BARRIER();
    }
    // h_168 in hbuf[0] and mlps.h

    // ---- B staging helpers ----
    auto stage_cn = [&](const f32x4& v) {
        if (lt < 64) {
            u16x4 oh, ol;
#pragma unroll
            for (int q = 0; q < 4; q++) {
                unsigned short hh, ll;
                splitT(v[q], hh, ll);
                oh[q] = hh; ol[q] = ll;
            }
            *(u16x4*)&mlps[rc * MS + 32 + cc]      = oh;
            *(u16x4*)&mlps[rc * MS + 64 + 32 + cc] = ol;
        }
    };
    auto stage_fc = [&](int t) {
        if (lt >= 64 && lt < 128) {
            int q = lt - 64;
            unsigned int v = fcs[t * 64 + q];
            mlps[(q >> 2) * MS + 48 + (q & 3)]      = (unsigned short)(v >> 16);
            mlps[(q >> 2) * MS + 64 + 48 + (q & 3)] = (unsigned short)(v & 0xFFFFu);
        }
    };
    auto mlp1 = [&]() {
        const int mbase = l15 * MS + l4 * 8;
        bf16x8 m0  = BC8(*(const u32x4*)&mlps[mbase]);
        bf16x8 m1  = BC8(*(const u32x4*)&mlps[mbase + 32]);
        bf16x8 m0l = BC8(*(const u32x4*)&mlps[mbase + 64]);
        bf16x8 m1l = BC8(*(const u32x4*)&mlps[mbase + 96]);
        f32x4 ha = {0.f,0.f,0.f,0.f}, hb = {0.f,0.f,0.f,0.f};
        ha = MFMA16(m0,  fW10h, ha);   hb = MFMA16(m1,  fW11h, hb);
        ha = MFMA16(m0l, fW10h, ha);   hb = MFMA16(m1l, fW11h, hb);
        ha = MFMA16(m0,  fW10l, ha);   hb = MFMA16(m1,  fW11l, hb);
        f32x4 hacc = ha + hb;
#pragma unroll
        for (int q = 0; q < 4; q++) {
            float hv = fmaxf(hacc[q] + b1j, 0.0f);
            unsigned short hh, ll;
            splitT(hv, hh, ll);
            hids[(l4 * 4 + q) * MS + j1]      = hh;
            hids[(l4 * 4 + q) * MS + 64 + j1] = ll;
        }
    };
    auto mlp2 = [&]() {
        const int mbase = l15 * MS + l4 * 8;
        bf16x8 h0  = BC8(*(const u32x4*)&hids[mbase]);
        bf16x8 h1  = BC8(*(const u32x4*)&hids[mbase + 32]);
        bf16x8 h0l = BC8(*(const u32x4*)&hids[mbase + 64]);
        bf16x8 h1l = BC8(*(const u32x4*)&hids[mbase + 96]);
        f32x4 oa = {0.f,0.f,0.f,0.f}, ob = {0.f,0.f,0.f,0.f};
        oa = MFMA16(h0,  fW20h, oa);   ob = MFMA16(h1,  fW21h, ob);
        oa = MFMA16(h0l, fW20h, oa);   ob = MFMA16(h1l, fW21h, ob);
        oa = MFMA16(h0,  fW20l, oa);   ob = MFMA16(h1,  fW21l, ob);
        f32x4 oacc = oa + ob;
        lat0 += oacc[0] + b2j;
        lat1 += oacc[1] + b2j;
        lat2 += oacc[2] + b2j;
        lat3 += oacc[3] + b2j;
    };

    // ---- post-encoder MLP (B) ----
    if (!gA) { stage_cn(creg); stage_fc(0); }
    BARRIER();
    if (!gA) mlp1();
    BARRIER();
    if (!gA) mlp2();

    // ---- decoder: 48 steps, 3 barriers each ----
    for (int t = 0; t < 48; ++t) {
        const int p = t & 1;
        if (!gA) {
            unsigned short bh, bl;
            splitT(lat0, bh, bl);
            xbuf[(l4 * 4 + 0) * XS2 + j1] = bh; xbuf[(l4 * 4 + 0) * XS2 + 64 + j1] = bl;
            splitT(lat1, bh, bl);
            xbuf[(l4 * 4 + 1) * XS2 + j1] = bh; xbuf[(l4 * 4 + 1) * XS2 + 64 + j1] = bl;
            splitT(lat2, bh, bl);
            xbuf[(l4 * 4 + 2) * XS2 + j1] = bh; xbuf[(l4 * 4 + 2) * XS2 + 64 + j1] = bl;
            splitT(lat3, bh, bl);
            xbuf[(l4 * 4 + 3) * XS2 + j1] = bh; xbuf[(l4 * 4 + 3) * XS2 + 64 + j1] = bl;
            stage_cn(creg);
            stage_fc(t);
            int tn = (t < 47) ? t + 1 : 47;
            if (lt < 64)
                creg = *(const f32x4*)(control + ((size_t)(b0 + rc) * 48 + tn) * 16 + cc);
        }
        BARRIER();   // B1: xn/cn/fc staged

        if (gA) {
            const unsigned short* hr = hbuf[p];
            const int xb = l15 * XS2 + l4 * 8;
            bf16x8 a0h = BC8(*(const u32x4*)&xbuf[xb]);
            bf16x8 a1h = BC8(*(const u32x4*)&xbuf[xb + 32]);
            bf16x8 a0l = BC8(*(const u32x4*)&xbuf[xb + 64]);
            bf16x8 a1l = BC8(*(const u32x4*)&xbuf[xb + 96]);
            bf16x8 a2h = BC8(*(const u32x4*)&hr[l15 * HS2 + l4 * 8]);
            bf16x8 a2l = BC8(*(const u32x4*)&hr[l15 * HS2 + 32 + l4 * 8]);
            f32x4 z0a = {0.f,0.f,0.f,0.f}, z0b = {0.f,0.f,0.f,0.f};
            f32x4 z1a = {0.f,0.f,0.f,0.f}, z1b = {0.f,0.f,0.f,0.f};
            z0a = MFMA16(a0h, fA0h, z0a);  z1a = MFMA16(a0h, fB0h, z1a);
            z0b = MFMA16(a1h, fA1h, z0b);  z1b = MFMA16(a1h, fB1h, z1b);
            z0a = MFMA16(a2h, fA2h, z0a);  z1a = MFMA16(a2h, fB2h, z1a);
            z0b = MFMA16(a0l, fA0h, z0b);  z1b = MFMA16(a0l, fB0h, z1b);
            z0a = MFMA16(a1l, fA1h, z0a);  z1a = MFMA16(a1l, fB1h, z1a);
            z0b = MFMA16(a2l, fA2h, z0b);  z1b = MFMA16(a2l, fB2h, z1b);
            z0a = MFMA16(a0h, fA0l, z0a);  z1a = MFMA16(a0h, fB0l, z1a);
            z0b = MFMA16(a1h, fA1l, z0b);  z1b = MFMA16(a1h, fB1l, z1b);
            z0a = MFMA16(a2h, fA2l, z0a);  z1a = MFMA16(a2h, fB2l, z1a);
            f32x4 z0 = z0a + z0b, z1 = z1a + z1b;
            lstm_gates(z0, z1, hbuf[p ^ 1], true);
        }
        BARRIER();   // B2: h ready

        if (!gA) mlp1();
        BARRIER();   // B3: hids ready

        if (!gA) {
            mlp2();
            out[((size_t)(b0 + l4 * 4 + 0) * 48 + t) * 64 + j1] = lat0;
            out[((size_t)(b0 + l4 * 4 + 1) * 48 + t) * 64 + j1] = lat1;
            out[((size_t)(b0 + l4 * 4 + 2) * 48 + t) * 64 + j1] = lat2;
            out[((size_t)(b0 + l4 * 4 + 3) * 48 + t) * 64 + j1] = lat3;
        }
    }
}

extern "C" void kernel_launch(void* const* d_in, const int* in_sizes, int n_in,
                              void* d_out, int out_size, void* d_ws, size_t ws_size,
                              hipStream_t stream) {
    tutina_kernel<<<dim3(256), dim3(512), 0, stream>>>(
        (const float*)d_in[0],  (const float*)d_in[1],  (const float*)d_in[2],
        (const float*)d_in[3],  (const float*)d_in[4],  (const float*)d_in[5],
        (const float*)d_in[6],  (const float*)d_in[7],  (const float*)d_in[8],
        (const float*)d_in[9],  (const float*)d_in[10], (const float*)d_in[11],
        (const float*)d_in[12], (const float*)d_in[13], (const float*)d_in[14],
        (const float*)d_in[15], (const float*)d_in[16], (const float*)d_in[17],
        (float*)d_out);
}